// Round 1
// baseline (646.759 us; speedup 1.0000x reference)
//
#include <hip/hip_runtime.h>

#define N_USERS 50000
#define N_ITEMS 100000
#define N_NODES (N_USERS + N_ITEMS)
#define DIM 64

// ---------------------------------------------------------------------------
// init: buf0 = concat(user, item); out = same (acc starts at emb); buf1 = 0
// all float4-vectorized (sizes are multiples of 4)
// ---------------------------------------------------------------------------
__global__ void init_kernel(const float4* __restrict__ user,
                            const float4* __restrict__ item,
                            float4* __restrict__ buf0,
                            float4* __restrict__ out,
                            float4* __restrict__ buf1,
                            int nUser4, int nTotal4) {
    int stride = gridDim.x * blockDim.x;
    for (int i = blockIdx.x * blockDim.x + threadIdx.x; i < nTotal4; i += stride) {
        float4 v = (i < nUser4) ? user[i] : item[i - nUser4];
        buf0[i] = v;
        out[i]  = v;
        buf1[i] = make_float4(0.f, 0.f, 0.f, 0.f);
    }
}

// ---------------------------------------------------------------------------
// spmm: dst[r, :] += vals[e] * src[c, :]  -- one 64-lane wave per edge,
// lane = dim. Gather and atomic scatter are each one contiguous 256B/wave.
// ---------------------------------------------------------------------------
__global__ void spmm_kernel(const int* __restrict__ rows,
                            const int* __restrict__ cols,
                            const float* __restrict__ vals,
                            const float* __restrict__ src,
                            float* __restrict__ dst,
                            int nEdges) {
    int lane  = threadIdx.x & 63;
    int wave  = (blockIdx.x * blockDim.x + threadIdx.x) >> 6;
    int nWave = (gridDim.x * blockDim.x) >> 6;
    for (int e = wave; e < nEdges; e += nWave) {
        int   r = rows[e];
        int   c = cols[e];
        float v = vals[e];
        float m = src[(size_t)c * DIM + lane] * v;
        atomicAdd(&dst[(size_t)r * DIM + lane], m);
    }
}

// ---------------------------------------------------------------------------
// accum + zero next dst: out += e; zbuf = 0
// ---------------------------------------------------------------------------
__global__ void accum_zero_kernel(float4* __restrict__ out,
                                  const float4* __restrict__ e,
                                  float4* __restrict__ zbuf,
                                  int n4) {
    int stride = gridDim.x * blockDim.x;
    for (int i = blockIdx.x * blockDim.x + threadIdx.x; i < n4; i += stride) {
        float4 o = out[i];
        float4 x = e[i];
        o.x += x.x; o.y += x.y; o.z += x.z; o.w += x.w;
        out[i]  = o;
        zbuf[i] = make_float4(0.f, 0.f, 0.f, 0.f);
    }
}

// ---------------------------------------------------------------------------
// final: out = (out + e) * (1/3)
// ---------------------------------------------------------------------------
__global__ void final_kernel(float4* __restrict__ out,
                             const float4* __restrict__ e,
                             int n4) {
    const float s = 1.0f / 3.0f;
    int stride = gridDim.x * blockDim.x;
    for (int i = blockIdx.x * blockDim.x + threadIdx.x; i < n4; i += stride) {
        float4 o = out[i];
        float4 x = e[i];
        o.x = (o.x + x.x) * s;
        o.y = (o.y + x.y) * s;
        o.z = (o.z + x.z) * s;
        o.w = (o.w + x.w) * s;
        out[i] = o;
    }
}

extern "C" void kernel_launch(void* const* d_in, const int* in_sizes, int n_in,
                              void* d_out, int out_size, void* d_ws, size_t ws_size,
                              hipStream_t stream) {
    const float* user = (const float*)d_in[0];
    const float* item = (const float*)d_in[1];
    const int*   rows = (const int*)d_in[2];
    const int*   cols = (const int*)d_in[3];
    const float* vals = (const float*)d_in[4];
    float* out = (float*)d_out;

    float* buf0 = (float*)d_ws;                          // [N_NODES * DIM]
    float* buf1 = buf0 + (size_t)N_NODES * DIM;          // [N_NODES * DIM]

    const int nEdges  = in_sizes[2];
    const int n4      = N_NODES * DIM / 4;
    const int nUser4  = N_USERS * DIM / 4;

    // SpMM grid: wave per edge, 4 waves/block, capped + grid-stride
    long long spmmThreads = (long long)nEdges * 64;
    int spmmBlocks = (int)((spmmThreads + 255) / 256);
    if (spmmBlocks > 65536) spmmBlocks = 65536;

    // 1. acc = emb, buf0 = emb, buf1 = 0
    init_kernel<<<2048, 256, 0, stream>>>((const float4*)user, (const float4*)item,
                                          (float4*)buf0, (float4*)out, (float4*)buf1,
                                          nUser4, n4);
    // 2. e1 = A @ buf0  -> buf1
    spmm_kernel<<<spmmBlocks, 256, 0, stream>>>(rows, cols, vals, buf0, buf1, nEdges);
    // 3. acc += e1; zero buf0 for next dst
    accum_zero_kernel<<<2048, 256, 0, stream>>>((float4*)out, (const float4*)buf1,
                                                (float4*)buf0, n4);
    // 4. e2 = A @ buf1 -> buf0
    spmm_kernel<<<spmmBlocks, 256, 0, stream>>>(rows, cols, vals, buf1, buf0, nEdges);
    // 5. acc = (acc + e2) / 3
    final_kernel<<<2048, 256, 0, stream>>>((float4*)out, (const float4*)buf0, n4);
}

// Round 2
// 401.608 us; speedup vs baseline: 1.6104x; 1.6104x over previous
//
#include <hip/hip_runtime.h>

#define N_USERS 50000
#define N_ITEMS 100000
#define N_NODES (N_USERS + N_ITEMS)
#define DIM 64
#define SCAN_CHUNK 256
#define NBLK_SCAN ((N_NODES + SCAN_CHUNK - 1) / SCAN_CHUNK)   // 586

// ---------------------------------------------------------------------------
// init: buf0 = concat(user, item) (float4 vectorized); counts = 0
// ---------------------------------------------------------------------------
__global__ void init_kernel(const float4* __restrict__ user,
                            const float4* __restrict__ item,
                            float4* __restrict__ buf0,
                            int* __restrict__ counts,
                            int nUser4, int nTotal4) {
    int stride = gridDim.x * blockDim.x;
    int t0 = blockIdx.x * blockDim.x + threadIdx.x;
    for (int i = t0; i < nTotal4; i += stride) {
        buf0[i] = (i < nUser4) ? user[i] : item[i - nUser4];
    }
    for (int i = t0; i < N_NODES; i += stride) counts[i] = 0;
}

// ---------------------------------------------------------------------------
// histogram of destination rows
// ---------------------------------------------------------------------------
__global__ void hist_kernel(const int* __restrict__ rows,
                            int* __restrict__ counts, int nE) {
    int i = blockIdx.x * blockDim.x + threadIdx.x;
    if (i < nE) atomicAdd(&counts[rows[i]], 1);
}

// ---------------------------------------------------------------------------
// scan level 1: per-256-chunk sums
// ---------------------------------------------------------------------------
__global__ void partial_kernel(const int* __restrict__ counts,
                               int* __restrict__ partials) {
    __shared__ int lds[SCAN_CHUNK];
    int i = blockIdx.x * SCAN_CHUNK + threadIdx.x;
    lds[threadIdx.x] = (i < N_NODES) ? counts[i] : 0;
    __syncthreads();
    for (int off = SCAN_CHUNK / 2; off > 0; off >>= 1) {
        if (threadIdx.x < off) lds[threadIdx.x] += lds[threadIdx.x + off];
        __syncthreads();
    }
    if (threadIdx.x == 0) partials[blockIdx.x] = lds[0];
}

// ---------------------------------------------------------------------------
// scan level 2: exclusive scan of the 586 chunk sums (one 1024-thread block)
// ---------------------------------------------------------------------------
__global__ void scanp_kernel(const int* __restrict__ partials,
                             int* __restrict__ chunkoff) {
    __shared__ int lds[1024];
    int t = threadIdx.x;
    lds[t] = (t < NBLK_SCAN) ? partials[t] : 0;
    __syncthreads();
    for (int off = 1; off < 1024; off <<= 1) {
        int v = (t >= off) ? lds[t - off] : 0;
        __syncthreads();
        lds[t] += v;
        __syncthreads();
    }
    if (t < NBLK_SCAN) chunkoff[t] = (t == 0) ? 0 : lds[t - 1];
}

// ---------------------------------------------------------------------------
// scan level 3: row_start[i] = chunkoff + exclusive-within-chunk; cursor = same
// ---------------------------------------------------------------------------
__global__ void rowstart_kernel(const int* __restrict__ counts,
                                const int* __restrict__ chunkoff,
                                int* __restrict__ row_start,
                                int* __restrict__ cursor) {
    __shared__ int lds[SCAN_CHUNK];
    int i = blockIdx.x * SCAN_CHUNK + threadIdx.x;
    int t = threadIdx.x;
    int v = (i < N_NODES) ? counts[i] : 0;
    lds[t] = v;
    __syncthreads();
    for (int off = 1; off < SCAN_CHUNK; off <<= 1) {
        int w = (t >= off) ? lds[t - off] : 0;
        __syncthreads();
        lds[t] += w;
        __syncthreads();
    }
    if (i < N_NODES) {
        int rs = chunkoff[blockIdx.x] + (lds[t] - v);   // exclusive
        row_start[i] = rs;
        cursor[i] = rs;
    }
}

// ---------------------------------------------------------------------------
// scatter edges into CSR order as packed (col, val); cursor[r] ends at row end
// ---------------------------------------------------------------------------
__global__ void scatter_kernel(const int* __restrict__ rows,
                               const int* __restrict__ cols,
                               const float* __restrict__ vals,
                               int* __restrict__ cursor,
                               float2* __restrict__ edges, int nE) {
    int i = blockIdx.x * blockDim.x + threadIdx.x;
    if (i < nE) {
        int idx = atomicAdd(&cursor[rows[i]], 1);
        edges[idx] = make_float2(__int_as_float(cols[i]), vals[i]);
    }
}

// ---------------------------------------------------------------------------
// CSR SpMM, gather formulation: one 64-lane wave per dst row, lane = dim.
// MODE 0: dst[r] = sum              (layer 1: buf0 -> buf1)
// MODE 1: out[r] = (emb[r] + prev[r] + sum) / 3   (layer 2 + fused epilogue)
// After scatter, cursor[r] == row end, so [row_start[r], cursor[r]) is the row.
// ---------------------------------------------------------------------------
template <int MODE>
__global__ void spmm_csr_kernel(const int* __restrict__ row_start,
                                const int* __restrict__ row_end,
                                const float2* __restrict__ edges,
                                const float* __restrict__ src,
                                float* __restrict__ dst,
                                const float* __restrict__ emb,
                                const float* __restrict__ prev,
                                float* __restrict__ out) {
    int wave = (blockIdx.x * blockDim.x + threadIdx.x) >> 6;
    int lane = threadIdx.x & 63;
    if (wave >= N_NODES) return;
    int beg = row_start[wave];
    int end = row_end[wave];
    float acc = 0.f;
    int i = beg;
    // 2-unrolled so two gathers are in flight per trip
    for (; i + 1 < end; i += 2) {
        float2 e0 = edges[i];
        float2 e1 = edges[i + 1];
        float s0 = src[(size_t)__float_as_int(e0.x) * DIM + lane];
        float s1 = src[(size_t)__float_as_int(e1.x) * DIM + lane];
        acc = fmaf(e0.y, s0, acc);
        acc = fmaf(e1.y, s1, acc);
    }
    if (i < end) {
        float2 e0 = edges[i];
        acc = fmaf(e0.y, src[(size_t)__float_as_int(e0.x) * DIM + lane], acc);
    }
    size_t o = (size_t)wave * DIM + lane;
    if (MODE == 0) {
        dst[o] = acc;
    } else {
        out[o] = (emb[o] + prev[o] + acc) * (1.0f / 3.0f);
    }
}

extern "C" void kernel_launch(void* const* d_in, const int* in_sizes, int n_in,
                              void* d_out, int out_size, void* d_ws, size_t ws_size,
                              hipStream_t stream) {
    const float* user = (const float*)d_in[0];
    const float* item = (const float*)d_in[1];
    const int*   rows = (const int*)d_in[2];
    const int*   cols = (const int*)d_in[3];
    const float* vals = (const float*)d_in[4];
    float* out = (float*)d_out;

    const int nEdges = in_sizes[2];
    const int nNodeF = N_NODES * DIM;              // 9.6M floats

    // workspace layout (floats): buf0 | buf1 | edges(2*E) | ints...
    float*  buf0      = (float*)d_ws;
    float*  buf1      = buf0 + nNodeF;
    float2* edges     = (float2*)(buf1 + nNodeF);  // byte off 76.8MB, 8B-aligned
    int*    counts    = (int*)(edges + nEdges);
    int*    row_start = counts + N_NODES;
    int*    cursor    = row_start + N_NODES;
    int*    partials  = cursor + N_NODES;
    int*    chunkoff  = partials + NBLK_SCAN;

    const int n4     = nNodeF / 4;
    const int nUser4 = N_USERS * DIM / 4;
    const int eBlocks = (nEdges + 255) / 256;
    const int spmmBlocks = (N_NODES + 3) / 4;      // 4 waves/block, wave per row

    // 1. buf0 = emb, counts = 0
    init_kernel<<<2048, 256, 0, stream>>>((const float4*)user, (const float4*)item,
                                          (float4*)buf0, counts, nUser4, n4);
    // 2. CSR build
    hist_kernel<<<eBlocks, 256, 0, stream>>>(rows, counts, nEdges);
    partial_kernel<<<NBLK_SCAN, SCAN_CHUNK, 0, stream>>>(counts, partials);
    scanp_kernel<<<1, 1024, 0, stream>>>(partials, chunkoff);
    rowstart_kernel<<<NBLK_SCAN, SCAN_CHUNK, 0, stream>>>(counts, chunkoff,
                                                          row_start, cursor);
    scatter_kernel<<<eBlocks, 256, 0, stream>>>(rows, cols, vals, cursor,
                                                edges, nEdges);
    // 3. e1 = A @ emb -> buf1
    spmm_csr_kernel<0><<<spmmBlocks, 256, 0, stream>>>(row_start, cursor, edges,
                                                       buf0, buf1,
                                                       nullptr, nullptr, nullptr);
    // 4. out = (emb + e1 + A @ e1) / 3
    spmm_csr_kernel<1><<<spmmBlocks, 256, 0, stream>>>(row_start, cursor, edges,
                                                       buf1, nullptr,
                                                       buf0, buf1, out);
}

// Round 4
// 344.132 us; speedup vs baseline: 1.8794x; 1.1670x over previous
//
#include <hip/hip_runtime.h>
#include <hip/hip_fp16.h>

#define N_USERS 50000
#define N_ITEMS 100000
#define N_NODES (N_USERS + N_ITEMS)
#define DIM 64
#define SCAN_CHUNK 256
#define NBLK_SCAN ((N_NODES + SCAN_CHUNK - 1) / SCAN_CHUNK)   // 586

// ---------------------------------------------------------------------------
// init: buf0 = fp16(concat(user, item)); counts = 0
// each thread converts 4 floats -> 4 halves (8B store)
// ---------------------------------------------------------------------------
__global__ void init_kernel(const float4* __restrict__ user,
                            const float4* __restrict__ item,
                            uint2* __restrict__ buf0,
                            int* __restrict__ counts,
                            int nUser4, int nTotal4) {
    int stride = gridDim.x * blockDim.x;
    int t0 = blockIdx.x * blockDim.x + threadIdx.x;
    for (int i = t0; i < nTotal4; i += stride) {
        float4 v = (i < nUser4) ? user[i] : item[i - nUser4];
        __half2 h0 = __floats2half2_rn(v.x, v.y);
        __half2 h1 = __floats2half2_rn(v.z, v.w);
        uint2 o;
        o.x = *(const unsigned int*)&h0;
        o.y = *(const unsigned int*)&h1;
        buf0[i] = o;
    }
    for (int i = t0; i < N_NODES; i += stride) counts[i] = 0;
}

// ---------------------------------------------------------------------------
// histogram of destination rows
// ---------------------------------------------------------------------------
__global__ void hist_kernel(const int* __restrict__ rows,
                            int* __restrict__ counts, int nE) {
    int i = blockIdx.x * blockDim.x + threadIdx.x;
    if (i < nE) atomicAdd(&counts[rows[i]], 1);
}

// ---------------------------------------------------------------------------
// scan level 1: per-256-chunk sums
// ---------------------------------------------------------------------------
__global__ void partial_kernel(const int* __restrict__ counts,
                               int* __restrict__ partials) {
    __shared__ int lds[SCAN_CHUNK];
    int i = blockIdx.x * SCAN_CHUNK + threadIdx.x;
    lds[threadIdx.x] = (i < N_NODES) ? counts[i] : 0;
    __syncthreads();
    for (int off = SCAN_CHUNK / 2; off > 0; off >>= 1) {
        if (threadIdx.x < off) lds[threadIdx.x] += lds[threadIdx.x + off];
        __syncthreads();
    }
    if (threadIdx.x == 0) partials[blockIdx.x] = lds[0];
}

// ---------------------------------------------------------------------------
// scan level 2: exclusive scan of chunk sums (one 1024-thread block)
// ---------------------------------------------------------------------------
__global__ void scanp_kernel(const int* __restrict__ partials,
                             int* __restrict__ chunkoff) {
    __shared__ int lds[1024];
    int t = threadIdx.x;
    lds[t] = (t < NBLK_SCAN) ? partials[t] : 0;
    __syncthreads();
    for (int off = 1; off < 1024; off <<= 1) {
        int v = (t >= off) ? lds[t - off] : 0;
        __syncthreads();
        lds[t] += v;
        __syncthreads();
    }
    if (t < NBLK_SCAN) chunkoff[t] = (t == 0) ? 0 : lds[t - 1];
}

// ---------------------------------------------------------------------------
// scan level 3: row_start = chunkoff + exclusive-within-chunk; cursor = same
// ---------------------------------------------------------------------------
__global__ void rowstart_kernel(const int* __restrict__ counts,
                                const int* __restrict__ chunkoff,
                                int* __restrict__ row_start,
                                int* __restrict__ cursor) {
    __shared__ int lds[SCAN_CHUNK];
    int i = blockIdx.x * SCAN_CHUNK + threadIdx.x;
    int t = threadIdx.x;
    int v = (i < N_NODES) ? counts[i] : 0;
    lds[t] = v;
    __syncthreads();
    for (int off = 1; off < SCAN_CHUNK; off <<= 1) {
        int w = (t >= off) ? lds[t - off] : 0;
        __syncthreads();
        lds[t] += w;
        __syncthreads();
    }
    if (i < N_NODES) {
        int rs = chunkoff[blockIdx.x] + (lds[t] - v);   // exclusive
        row_start[i] = rs;
        cursor[i] = rs;
    }
}

// ---------------------------------------------------------------------------
// scatter edges into CSR order as packed (col, val)
// ---------------------------------------------------------------------------
__global__ void scatter_kernel(const int* __restrict__ rows,
                               const int* __restrict__ cols,
                               const float* __restrict__ vals,
                               int* __restrict__ cursor,
                               float2* __restrict__ edges, int nE) {
    int i = blockIdx.x * blockDim.x + threadIdx.x;
    if (i < nE) {
        int idx = atomicAdd(&cursor[rows[i]], 1);
        edges[idx] = make_float2(__int_as_float(cols[i]), vals[i]);
    }
}

// ---------------------------------------------------------------------------
// CSR SpMM, gather form. Wave per dst row, lane = dim, fp16 src features.
// Sized unroll blocks (8/4/2/1): all edge loads + gathers in a block are
// independent -> one latency exposure per block instead of per edge.
// MODE 0: dstH[r] = fp16(sum)
// MODE 1: out[r] = (emb_fp32[r] + prev[r] + sum) / 3
// ---------------------------------------------------------------------------
#define GBLOCK(U)                                                              \
    {                                                                          \
        float2 ev[U];                                                          \
        _Pragma("unroll") for (int j = 0; j < U; ++j) ev[j] = edges[i + j];    \
        float sv[U];                                                           \
        _Pragma("unroll") for (int j = 0; j < U; ++j)                          \
            sv[j] = __half2float(                                              \
                src[(size_t)__float_as_int(ev[j].x) * DIM + lane]);            \
        _Pragma("unroll") for (int j = 0; j < U; ++j)                          \
            acc = fmaf(ev[j].y, sv[j], acc);                                   \
        i += U;                                                                \
    }

template <int MODE>
__global__ void spmm_csr_kernel(const int* __restrict__ row_start,
                                const int* __restrict__ row_end,
                                const float2* __restrict__ edges,
                                const __half* __restrict__ src,
                                __half* __restrict__ dstH,
                                const float* __restrict__ user,
                                const float* __restrict__ item,
                                const __half* __restrict__ prev,
                                float* __restrict__ out) {
    int wave = (blockIdx.x * blockDim.x + threadIdx.x) >> 6;
    int lane = threadIdx.x & 63;
    if (wave >= N_NODES) return;
    int i   = row_start[wave];
    int end = row_end[wave];
    float acc = 0.f;

    while (end - i >= 8) GBLOCK(8)
    if (end - i >= 4)    GBLOCK(4)
    if (end - i >= 2)    GBLOCK(2)
    if (end - i >= 1)    GBLOCK(1)

    size_t o = (size_t)wave * DIM + lane;
    if (MODE == 0) {
        dstH[o] = __float2half(acc);
    } else {
        float emb = (wave < N_USERS) ? user[o]
                                     : item[o - (size_t)N_USERS * DIM];
        out[o] = (emb + __half2float(prev[o]) + acc) * (1.0f / 3.0f);
    }
}

extern "C" void kernel_launch(void* const* d_in, const int* in_sizes, int n_in,
                              void* d_out, int out_size, void* d_ws, size_t ws_size,
                              hipStream_t stream) {
    const float* user = (const float*)d_in[0];
    const float* item = (const float*)d_in[1];
    const int*   rows = (const int*)d_in[2];
    const int*   cols = (const int*)d_in[3];
    const float* vals = (const float*)d_in[4];
    float* out = (float*)d_out;

    const int    nEdges = in_sizes[2];
    const size_t nNodeF = (size_t)N_NODES * DIM;      // 9.6M elements

    // workspace: buf0(half) | buf1(half) | edges(float2 E) | ints
    __half* buf0      = (__half*)d_ws;
    __half* buf1      = buf0 + nNodeF;
    float2* edges     = (float2*)(buf1 + nNodeF);     // byte off 38.4MB, 8B-aligned
    int*    counts    = (int*)(edges + nEdges);
    int*    row_start = counts + N_NODES;
    int*    cursor    = row_start + N_NODES;
    int*    partials  = cursor + N_NODES;
    int*    chunkoff  = partials + NBLK_SCAN;

    const int n4      = (int)(nNodeF / 4);
    const int nUser4  = N_USERS * DIM / 4;
    const int eBlocks = (nEdges + 255) / 256;
    const int spmmBlocks = (N_NODES + 3) / 4;         // 4 waves/block

    // 1. buf0 = fp16(emb), counts = 0
    init_kernel<<<2048, 256, 0, stream>>>((const float4*)user, (const float4*)item,
                                          (uint2*)buf0, counts, nUser4, n4);
    // 2. CSR build
    hist_kernel<<<eBlocks, 256, 0, stream>>>(rows, counts, nEdges);
    partial_kernel<<<NBLK_SCAN, SCAN_CHUNK, 0, stream>>>(counts, partials);
    scanp_kernel<<<1, 1024, 0, stream>>>(partials, chunkoff);
    rowstart_kernel<<<NBLK_SCAN, SCAN_CHUNK, 0, stream>>>(counts, chunkoff,
                                                          row_start, cursor);
    scatter_kernel<<<eBlocks, 256, 0, stream>>>(rows, cols, vals, cursor,
                                                edges, nEdges);
    // 3. e1 = A @ emb -> buf1 (fp16)
    spmm_csr_kernel<0><<<spmmBlocks, 256, 0, stream>>>(row_start, cursor, edges,
                                                       buf0, buf1,
                                                       nullptr, nullptr, nullptr,
                                                       nullptr);
    // 4. out = (emb_fp32 + e1 + A @ e1) / 3
    spmm_csr_kernel<1><<<spmmBlocks, 256, 0, stream>>>(row_start, cursor, edges,
                                                       buf1, nullptr,
                                                       user, item, buf1, out);
}

// Round 5
// 311.294 us; speedup vs baseline: 2.0776x; 1.1055x over previous
//
#include <hip/hip_runtime.h>
#include <hip/hip_fp16.h>

#define N_USERS 50000
#define N_ITEMS 100000
#define N_NODES (N_USERS + N_ITEMS)
#define DIM 64
#define D2  (DIM / 2)                 // half2 elements per row
#define SCAN_CHUNK 256
#define NBLK_SCAN ((N_NODES + SCAN_CHUNK - 1) / SCAN_CHUNK)   // 586
#define NXCD 8
#define ROWS_PER_XCD ((N_NODES + NXCD - 1) / NXCD)            // 18750
#define XCD_CHUNKS 64

// ---------------------------------------------------------------------------
// init: buf0 = fp16(concat(user, item)); counts = 0
// ---------------------------------------------------------------------------
__global__ void init_kernel(const float4* __restrict__ user,
                            const float4* __restrict__ item,
                            uint2* __restrict__ buf0,
                            int* __restrict__ counts,
                            int nUser4, int nTotal4) {
    int stride = gridDim.x * blockDim.x;
    int t0 = blockIdx.x * blockDim.x + threadIdx.x;
    for (int i = t0; i < nTotal4; i += stride) {
        float4 v = (i < nUser4) ? user[i] : item[i - nUser4];
        __half2 h0 = __floats2half2_rn(v.x, v.y);
        __half2 h1 = __floats2half2_rn(v.z, v.w);
        uint2 o;
        o.x = *(const unsigned int*)&h0;
        o.y = *(const unsigned int*)&h1;
        buf0[i] = o;
    }
    for (int i = t0; i < N_NODES; i += stride) counts[i] = 0;
}

// ---------------------------------------------------------------------------
// histogram of destination rows
// ---------------------------------------------------------------------------
__global__ void hist_kernel(const int* __restrict__ rows,
                            int* __restrict__ counts, int nE) {
    int i = blockIdx.x * blockDim.x + threadIdx.x;
    if (i < nE) atomicAdd(&counts[rows[i]], 1);
}

// ---------------------------------------------------------------------------
// scan level 1: per-256-chunk sums
// ---------------------------------------------------------------------------
__global__ void partial_kernel(const int* __restrict__ counts,
                               int* __restrict__ partials) {
    __shared__ int lds[SCAN_CHUNK];
    int i = blockIdx.x * SCAN_CHUNK + threadIdx.x;
    lds[threadIdx.x] = (i < N_NODES) ? counts[i] : 0;
    __syncthreads();
    for (int off = SCAN_CHUNK / 2; off > 0; off >>= 1) {
        if (threadIdx.x < off) lds[threadIdx.x] += lds[threadIdx.x + off];
        __syncthreads();
    }
    if (threadIdx.x == 0) partials[blockIdx.x] = lds[0];
}

// ---------------------------------------------------------------------------
// scan level 2: exclusive scan of chunk sums (one 1024-thread block)
// ---------------------------------------------------------------------------
__global__ void scanp_kernel(const int* __restrict__ partials,
                             int* __restrict__ chunkoff) {
    __shared__ int lds[1024];
    int t = threadIdx.x;
    lds[t] = (t < NBLK_SCAN) ? partials[t] : 0;
    __syncthreads();
    for (int off = 1; off < 1024; off <<= 1) {
        int v = (t >= off) ? lds[t - off] : 0;
        __syncthreads();
        lds[t] += v;
        __syncthreads();
    }
    if (t < NBLK_SCAN) chunkoff[t] = (t == 0) ? 0 : lds[t - 1];
}

// ---------------------------------------------------------------------------
// scan level 3: row_start = chunkoff + exclusive-within-chunk; cursor = same
// ---------------------------------------------------------------------------
__global__ void rowstart_kernel(const int* __restrict__ counts,
                                const int* __restrict__ chunkoff,
                                int* __restrict__ row_start,
                                int* __restrict__ cursor) {
    __shared__ int lds[SCAN_CHUNK];
    int i = blockIdx.x * SCAN_CHUNK + threadIdx.x;
    int t = threadIdx.x;
    int v = (i < N_NODES) ? counts[i] : 0;
    lds[t] = v;
    __syncthreads();
    for (int off = 1; off < SCAN_CHUNK; off <<= 1) {
        int w = (t >= off) ? lds[t - off] : 0;
        __syncthreads();
        lds[t] += w;
        __syncthreads();
    }
    if (i < N_NODES) {
        int rs = chunkoff[blockIdx.x] + (lds[t] - v);   // exclusive
        row_start[i] = rs;
        cursor[i] = rs;
    }
}

// ---------------------------------------------------------------------------
// XCD-partitioned scatter. blockIdx%8 is (empirically) the XCD; each XCD
// scatters only rows in its contiguous range -> its CSR write window is
// ~1.2MB, L2-resident on that XCD only, so 64B lines collect all their 8B
// edge stores before one full-line writeback. Reads are replicated 8x
// (coalesced, L3-served). Correct regardless of the actual block->XCD map.
// ---------------------------------------------------------------------------
__global__ void scatter_xcd_kernel(const int* __restrict__ rows,
                                   const int* __restrict__ cols,
                                   const float* __restrict__ vals,
                                   int* __restrict__ cursor,
                                   float2* __restrict__ edges, int nE) {
    int xcd   = blockIdx.x & (NXCD - 1);
    int chunk = blockIdx.x >> 3;
    int chunkSz = (nE + XCD_CHUNKS - 1) / XCD_CHUNKS;
    int beg = chunk * chunkSz;
    int end = beg + chunkSz; if (end > nE) end = nE;
    for (int e = beg + threadIdx.x; e < end; e += blockDim.x) {
        int   r = rows[e];
        int   c = cols[e];
        float v = vals[e];
        if (r / ROWS_PER_XCD == xcd) {
            int idx = atomicAdd(&cursor[r], 1);
            edges[idx] = make_float2(__int_as_float(c), v);
        }
    }
}

// ---------------------------------------------------------------------------
// CSR SpMM, gather form, 2 rows per wave: lane = (half, d2), half-wave of 32
// lanes covers one row as 32 x half2. Doubles per-wave outstanding gathers
// (latency-bound loop). Sized unroll blocks 8/4/2/1.
// MODE 0: dst2[r] = fp16(sum)
// MODE 1: out2[r] = (emb_fp32[r] + prev[r] + sum) / 3
// ---------------------------------------------------------------------------
#define GBLOCK2(U)                                                             \
    {                                                                          \
        float2 ev[U];                                                          \
        _Pragma("unroll") for (int j = 0; j < U; ++j) ev[j] = edges[i + j];    \
        __half2 sv[U];                                                         \
        _Pragma("unroll") for (int j = 0; j < U; ++j)                          \
            sv[j] = src2[(size_t)__float_as_int(ev[j].x) * D2 + d2];           \
        _Pragma("unroll") for (int j = 0; j < U; ++j) {                        \
            float2 s = __half22float2(sv[j]);                                  \
            acc.x = fmaf(ev[j].y, s.x, acc.x);                                 \
            acc.y = fmaf(ev[j].y, s.y, acc.y);                                 \
        }                                                                      \
        i += U;                                                                \
    }

template <int MODE>
__global__ void spmm_csr2_kernel(const int* __restrict__ row_start,
                                 const int* __restrict__ row_end,
                                 const float2* __restrict__ edges,
                                 const __half2* __restrict__ src2,
                                 __half2* __restrict__ dst2,
                                 const float2* __restrict__ user2,
                                 const float2* __restrict__ item2,
                                 const __half2* __restrict__ prev2,
                                 float2* __restrict__ out2) {
    int wave = (blockIdx.x * blockDim.x + threadIdx.x) >> 6;
    int lane = threadIdx.x & 63;
    int half = lane >> 5;
    int d2   = lane & 31;
    int row  = wave * 2 + half;
    if (row >= N_NODES) return;
    int i   = row_start[row];
    int end = row_end[row];
    float2 acc = make_float2(0.f, 0.f);

    while (end - i >= 8) GBLOCK2(8)
    if (end - i >= 4)    GBLOCK2(4)
    if (end - i >= 2)    GBLOCK2(2)
    if (end - i >= 1)    GBLOCK2(1)

    size_t o = (size_t)row * D2 + d2;
    if (MODE == 0) {
        dst2[o] = __floats2half2_rn(acc.x, acc.y);
    } else {
        float2 emb = (row < N_USERS) ? user2[o]
                                     : item2[o - (size_t)N_USERS * D2];
        float2 p = __half22float2(prev2[o]);
        out2[o] = make_float2((emb.x + p.x + acc.x) * (1.0f / 3.0f),
                              (emb.y + p.y + acc.y) * (1.0f / 3.0f));
    }
}

extern "C" void kernel_launch(void* const* d_in, const int* in_sizes, int n_in,
                              void* d_out, int out_size, void* d_ws, size_t ws_size,
                              hipStream_t stream) {
    const float* user = (const float*)d_in[0];
    const float* item = (const float*)d_in[1];
    const int*   rows = (const int*)d_in[2];
    const int*   cols = (const int*)d_in[3];
    const float* vals = (const float*)d_in[4];
    float* out = (float*)d_out;

    const int    nEdges = in_sizes[2];
    const size_t nNodeF = (size_t)N_NODES * DIM;      // 9.6M elements

    // workspace: buf0(half) | buf1(half) | edges(float2 E) | ints
    __half* buf0      = (__half*)d_ws;
    __half* buf1      = buf0 + nNodeF;
    float2* edges     = (float2*)(buf1 + nNodeF);     // 8B-aligned
    int*    counts    = (int*)(edges + nEdges);
    int*    row_start = counts + N_NODES;
    int*    cursor    = row_start + N_NODES;
    int*    partials  = cursor + N_NODES;
    int*    chunkoff  = partials + NBLK_SCAN;

    const int n4      = (int)(nNodeF / 4);
    const int nUser4  = N_USERS * DIM / 4;
    const int eBlocks = (nEdges + 255) / 256;
    const int nWaves  = (N_NODES + 1) / 2;            // 2 rows per wave
    const int spmmBlocks = (nWaves + 3) / 4;          // 4 waves/block

    // 1. buf0 = fp16(emb), counts = 0
    init_kernel<<<2048, 256, 0, stream>>>((const float4*)user, (const float4*)item,
                                          (uint2*)buf0, counts, nUser4, n4);
    // 2. CSR build
    hist_kernel<<<eBlocks, 256, 0, stream>>>(rows, counts, nEdges);
    partial_kernel<<<NBLK_SCAN, SCAN_CHUNK, 0, stream>>>(counts, partials);
    scanp_kernel<<<1, 1024, 0, stream>>>(partials, chunkoff);
    rowstart_kernel<<<NBLK_SCAN, SCAN_CHUNK, 0, stream>>>(counts, chunkoff,
                                                          row_start, cursor);
    scatter_xcd_kernel<<<NXCD * XCD_CHUNKS, 256, 0, stream>>>(rows, cols, vals,
                                                              cursor, edges, nEdges);
    // 3. e1 = A @ emb -> buf1 (fp16)
    spmm_csr2_kernel<0><<<spmmBlocks, 256, 0, stream>>>(row_start, cursor, edges,
                                                        (const __half2*)buf0,
                                                        (__half2*)buf1,
                                                        nullptr, nullptr, nullptr,
                                                        nullptr);
    // 4. out = (emb_fp32 + e1 + A @ e1) / 3
    spmm_csr2_kernel<1><<<spmmBlocks, 256, 0, stream>>>(row_start, cursor, edges,
                                                        (const __half2*)buf1,
                                                        nullptr,
                                                        (const float2*)user,
                                                        (const float2*)item,
                                                        (const __half2*)buf1,
                                                        (float2*)out);
}

// Round 6
// 293.430 us; speedup vs baseline: 2.2041x; 1.0609x over previous
//
#include <hip/hip_runtime.h>
#include <hip/hip_fp16.h>

#define N_USERS 50000
#define N_ITEMS 100000
#define N_NODES (N_USERS + N_ITEMS)
#define DIM 64
#define D2  (DIM / 2)                 // half2 elements per row
#define SCAN_CHUNK 256
#define NBLK_SCAN ((N_NODES + SCAN_CHUNK - 1) / SCAN_CHUNK)   // 586
#define NXCD 8
#define ROWS_PER_XCD ((N_NODES + NXCD - 1) / NXCD)            // 18750
#define XCD_CHUNKS 256

// ---------------------------------------------------------------------------
// init: buf0 = fp16(concat(user, item)); counts = 0
// ---------------------------------------------------------------------------
__global__ void init_kernel(const float4* __restrict__ user,
                            const float4* __restrict__ item,
                            uint2* __restrict__ buf0,
                            int* __restrict__ counts,
                            int nUser4, int nTotal4) {
    int stride = gridDim.x * blockDim.x;
    int t0 = blockIdx.x * blockDim.x + threadIdx.x;
    for (int i = t0; i < nTotal4; i += stride) {
        float4 v = (i < nUser4) ? user[i] : item[i - nUser4];
        __half2 h0 = __floats2half2_rn(v.x, v.y);
        __half2 h1 = __floats2half2_rn(v.z, v.w);
        uint2 o;
        o.x = *(const unsigned int*)&h0;
        o.y = *(const unsigned int*)&h1;
        buf0[i] = o;
    }
    for (int i = t0; i < N_NODES; i += stride) counts[i] = 0;
}

// ---------------------------------------------------------------------------
// histogram of destination rows
// ---------------------------------------------------------------------------
__global__ void hist_kernel(const int* __restrict__ rows,
                            int* __restrict__ counts, int nE) {
    int i = blockIdx.x * blockDim.x + threadIdx.x;
    if (i < nE) atomicAdd(&counts[rows[i]], 1);
}

// ---------------------------------------------------------------------------
// scan level 1: per-256-chunk sums
// ---------------------------------------------------------------------------
__global__ void partial_kernel(const int* __restrict__ counts,
                               int* __restrict__ partials) {
    __shared__ int lds[SCAN_CHUNK];
    int i = blockIdx.x * SCAN_CHUNK + threadIdx.x;
    lds[threadIdx.x] = (i < N_NODES) ? counts[i] : 0;
    __syncthreads();
    for (int off = SCAN_CHUNK / 2; off > 0; off >>= 1) {
        if (threadIdx.x < off) lds[threadIdx.x] += lds[threadIdx.x + off];
        __syncthreads();
    }
    if (threadIdx.x == 0) partials[blockIdx.x] = lds[0];
}

// ---------------------------------------------------------------------------
// scan level 2: exclusive scan of chunk sums (one 1024-thread block)
// ---------------------------------------------------------------------------
__global__ void scanp_kernel(const int* __restrict__ partials,
                             int* __restrict__ chunkoff) {
    __shared__ int lds[1024];
    int t = threadIdx.x;
    lds[t] = (t < NBLK_SCAN) ? partials[t] : 0;
    __syncthreads();
    for (int off = 1; off < 1024; off <<= 1) {
        int v = (t >= off) ? lds[t - off] : 0;
        __syncthreads();
        lds[t] += v;
        __syncthreads();
    }
    if (t < NBLK_SCAN) chunkoff[t] = (t == 0) ? 0 : lds[t - 1];
}

// ---------------------------------------------------------------------------
// scan level 3: row_start = chunkoff + exclusive-within-chunk; cursor = same
// ---------------------------------------------------------------------------
__global__ void rowstart_kernel(const int* __restrict__ counts,
                                const int* __restrict__ chunkoff,
                                int* __restrict__ row_start,
                                int* __restrict__ cursor) {
    __shared__ int lds[SCAN_CHUNK];
    int i = blockIdx.x * SCAN_CHUNK + threadIdx.x;
    int t = threadIdx.x;
    int v = (i < N_NODES) ? counts[i] : 0;
    lds[t] = v;
    __syncthreads();
    for (int off = 1; off < SCAN_CHUNK; off <<= 1) {
        int w = (t >= off) ? lds[t - off] : 0;
        __syncthreads();
        lds[t] += w;
        __syncthreads();
    }
    if (i < N_NODES) {
        int rs = chunkoff[blockIdx.x] + (lds[t] - v);   // exclusive
        row_start[i] = rs;
        cursor[i] = rs;
    }
}

// ---------------------------------------------------------------------------
// XCD-partitioned scatter, v2.
// Key change vs round 5: rows/cols/vals are read with NON-TEMPORAL loads
// (evict-first) so the 14.4MB/XCD replicated read stream no longer evicts
// the 1.2MB/XCD CSR write window from L2 -> 64B lines collect all ~8 of
// their 8B edge stores before one full-line writeback.
// Grid raised to 2048 blocks (= 8192 waves = full machine) for latency hiding.
// ---------------------------------------------------------------------------
__global__ void scatter_xcd_kernel(const int* __restrict__ rows,
                                   const int* __restrict__ cols,
                                   const float* __restrict__ vals,
                                   int* __restrict__ cursor,
                                   float2* __restrict__ edges, int nE) {
    int xcd   = blockIdx.x & (NXCD - 1);
    int chunk = blockIdx.x >> 3;
    int chunkSz = (nE + XCD_CHUNKS - 1) / XCD_CHUNKS;
    int beg = chunk * chunkSz;
    int end = beg + chunkSz; if (end > nE) end = nE;
    for (int e = beg + threadIdx.x; e < end; e += blockDim.x) {
        int   r = __builtin_nontemporal_load(rows + e);
        int   c = __builtin_nontemporal_load(cols + e);
        float v = __builtin_nontemporal_load(vals + e);
        if (r / ROWS_PER_XCD == xcd) {
            int idx = atomicAdd(&cursor[r], 1);
            edges[idx] = make_float2(__int_as_float(c), v);
        }
    }
}

// ---------------------------------------------------------------------------
// CSR SpMM, gather form, 2 rows per wave: lane = (half, d2), half-wave of 32
// lanes covers one row as 32 x half2. Sized unroll blocks 8/4/2/1.
// MODE 0: dst2[r] = fp16(sum)
// MODE 1: out2[r] = (emb_fp32[r] + prev[r] + sum) / 3
// ---------------------------------------------------------------------------
#define GBLOCK2(U)                                                             \
    {                                                                          \
        float2 ev[U];                                                          \
        _Pragma("unroll") for (int j = 0; j < U; ++j) ev[j] = edges[i + j];    \
        __half2 sv[U];                                                         \
        _Pragma("unroll") for (int j = 0; j < U; ++j)                          \
            sv[j] = src2[(size_t)__float_as_int(ev[j].x) * D2 + d2];           \
        _Pragma("unroll") for (int j = 0; j < U; ++j) {                        \
            float2 s = __half22float2(sv[j]);                                  \
            acc.x = fmaf(ev[j].y, s.x, acc.x);                                 \
            acc.y = fmaf(ev[j].y, s.y, acc.y);                                 \
        }                                                                      \
        i += U;                                                                \
    }

template <int MODE>
__global__ void spmm_csr2_kernel(const int* __restrict__ row_start,
                                 const int* __restrict__ row_end,
                                 const float2* __restrict__ edges,
                                 const __half2* __restrict__ src2,
                                 __half2* __restrict__ dst2,
                                 const float2* __restrict__ user2,
                                 const float2* __restrict__ item2,
                                 const __half2* __restrict__ prev2,
                                 float2* __restrict__ out2) {
    int wave = (blockIdx.x * blockDim.x + threadIdx.x) >> 6;
    int lane = threadIdx.x & 63;
    int half = lane >> 5;
    int d2   = lane & 31;
    int row  = wave * 2 + half;
    if (row >= N_NODES) return;
    int i   = row_start[row];
    int end = row_end[row];
    float2 acc = make_float2(0.f, 0.f);

    while (end - i >= 8) GBLOCK2(8)
    if (end - i >= 4)    GBLOCK2(4)
    if (end - i >= 2)    GBLOCK2(2)
    if (end - i >= 1)    GBLOCK2(1)

    size_t o = (size_t)row * D2 + d2;
    if (MODE == 0) {
        dst2[o] = __floats2half2_rn(acc.x, acc.y);
    } else {
        float2 emb = (row < N_USERS) ? user2[o]
                                     : item2[o - (size_t)N_USERS * D2];
        float2 p = __half22float2(prev2[o]);
        out2[o] = make_float2((emb.x + p.x + acc.x) * (1.0f / 3.0f),
                              (emb.y + p.y + acc.y) * (1.0f / 3.0f));
    }
}

extern "C" void kernel_launch(void* const* d_in, const int* in_sizes, int n_in,
                              void* d_out, int out_size, void* d_ws, size_t ws_size,
                              hipStream_t stream) {
    const float* user = (const float*)d_in[0];
    const float* item = (const float*)d_in[1];
    const int*   rows = (const int*)d_in[2];
    const int*   cols = (const int*)d_in[3];
    const float* vals = (const float*)d_in[4];
    float* out = (float*)d_out;

    const int    nEdges = in_sizes[2];
    const size_t nNodeF = (size_t)N_NODES * DIM;      // 9.6M elements

    // workspace: buf0(half) | buf1(half) | edges(float2 E) | ints
    __half* buf0      = (__half*)d_ws;
    __half* buf1      = buf0 + nNodeF;
    float2* edges     = (float2*)(buf1 + nNodeF);     // 8B-aligned
    int*    counts    = (int*)(edges + nEdges);
    int*    row_start = counts + N_NODES;
    int*    cursor    = row_start + N_NODES;
    int*    partials  = cursor + N_NODES;
    int*    chunkoff  = partials + NBLK_SCAN;

    const int n4      = (int)(nNodeF / 4);
    const int nUser4  = N_USERS * DIM / 4;
    const int eBlocks = (nEdges + 255) / 256;
    const int nWaves  = (N_NODES + 1) / 2;            // 2 rows per wave
    const int spmmBlocks = (nWaves + 3) / 4;          // 4 waves/block

    // 1. buf0 = fp16(emb), counts = 0
    init_kernel<<<2048, 256, 0, stream>>>((const float4*)user, (const float4*)item,
                                          (uint2*)buf0, counts, nUser4, n4);
    // 2. CSR build
    hist_kernel<<<eBlocks, 256, 0, stream>>>(rows, counts, nEdges);
    partial_kernel<<<NBLK_SCAN, SCAN_CHUNK, 0, stream>>>(counts, partials);
    scanp_kernel<<<1, 1024, 0, stream>>>(partials, chunkoff);
    rowstart_kernel<<<NBLK_SCAN, SCAN_CHUNK, 0, stream>>>(counts, chunkoff,
                                                          row_start, cursor);
    scatter_xcd_kernel<<<NXCD * XCD_CHUNKS, 256, 0, stream>>>(rows, cols, vals,
                                                              cursor, edges, nEdges);
    // 3. e1 = A @ emb -> buf1 (fp16)
    spmm_csr2_kernel<0><<<spmmBlocks, 256, 0, stream>>>(row_start, cursor, edges,
                                                        (const __half2*)buf0,
                                                        (__half2*)buf1,
                                                        nullptr, nullptr, nullptr,
                                                        nullptr);
    // 4. out = (emb_fp32 + e1 + A @ e1) / 3
    spmm_csr2_kernel<1><<<spmmBlocks, 256, 0, stream>>>(row_start, cursor, edges,
                                                        (const __half2*)buf1,
                                                        nullptr,
                                                        (const float2*)user,
                                                        (const float2*)item,
                                                        (const __half2*)buf1,
                                                        (float2*)out);
}